// Round 10
// baseline (3785.666 us; speedup 1.0000x reference)
//
#include <hip/hip_runtime.h>
#include <hip/hip_bf16.h>
#include <stdint.h>

typedef __bf16 bf16_t;
typedef bf16_t bf16x8 __attribute__((ext_vector_type(8)));
typedef float  f32x4  __attribute__((ext_vector_type(4)));
typedef float  f32x16 __attribute__((ext_vector_type(16)));

#define I_DIM 512
#define H_DIM 1024
#define B_DIM 64
#define S_DIM 512
#define G4    4096   // 4*H
#define CHUNK 16     // steps per xp ring slot
#define NCHUNK (S_DIM / CHUNK)
#define XPSLOT_ELEMS ((size_t)CHUNK * 64 * G4)   // 1024*4096 bf16 = 8 MB

// ---------------- workspace layout (bytes) — total ~34 MB ----------------
#define O_WXT   0x0000000ULL  // [4096][512]  bf16 = 4 MB   (packed WxT, row-major)
#define O_WHTF  0x0400000ULL  // [128][64][64][8] bf16 = 8 MB (Wh in MFMA B-frag order)
#define O_BIAS  0x0C00000ULL  // [4096] f32 = 16 KB
#define O_HBUF  0x0D00000ULL  // 2 slots * 128 KB (h in A-frag order) = 256 KB
#define O_BAR   0x0D40000ULL  // 32 KB counters: tree barrier + xp_done[] + consumed[]
#define O_XP    0x1200000ULL  // 2 slots * [1024][4096] bf16 = 16 MB

// bar[] u32 indices (64-spaced to avoid false sharing)
#define XPD_IDX(c)  (2048 + (c) * 64)   // xp chunk c published (128 xproj-WG arrivals)
#define CONS_IDX(c) (4096 + (c) * 64)   // xp chunk c consumed  (128 step-WG arrivals)

__device__ __forceinline__ float sigm(float x)      { return 1.f / (1.f + __expf(-x)); }
__device__ __forceinline__ float tanh_fast(float x) { return 1.f - 2.f / (__expf(2.f * x) + 1.f); }

// Packed gate-column permutation: packed col p = q*32 + g*8 + jj  <->  hidden j = q*8+jj, gate g (0:i 1:f 2:g 3:o)

__global__ void k_pack_wx(const float* __restrict__ w0, const float* __restrict__ w1,
                          const float* __restrict__ w2, const float* __restrict__ w3,
                          bf16_t* __restrict__ wxt) {
    int tid = blockIdx.x * 256 + threadIdx.x;
    int k = tid >> 12;
    int p = tid & 4095;
    int q = p >> 5, g = (p >> 3) & 3, jj = p & 7;
    int j = q * 8 + jj;
    const float* src = (g == 0) ? w0 : (g == 1) ? w1 : (g == 2) ? w2 : w3;
    wxt[(size_t)p * I_DIM + k] = (bf16_t)src[k * H_DIM + j];
}

// Wh -> global MFMA B-fragment order: whtf[q][ks][lane][8]
//   element = WhT[p = q*32 + (lane&31)][k = ks*16 + (lane>>5)*8 + e]
__global__ void k_pack_whf(const float* __restrict__ w0, const float* __restrict__ w1,
                           const float* __restrict__ w2, const float* __restrict__ w3,
                           bf16_t* __restrict__ whtf) {
    int idx = blockIdx.x * 256 + threadIdx.x;     // 0..4194303
    int e    = idx & 7;
    int lane = (idx >> 3) & 63;
    int ks   = (idx >> 9) & 63;
    int q    = idx >> 15;                          // 0..127
    int k = ks * 16 + (lane >> 5) * 8 + e;
    int c = lane & 31;
    int g = c >> 3, jj = c & 7;
    int j = q * 8 + jj;
    const float* src = (g == 0) ? w0 : (g == 1) ? w1 : (g == 2) ? w2 : w3;
    whtf[idx] = (bf16_t)src[k * H_DIM + j];
}

__global__ void k_pack_bias(const float* bi0, const float* bh0, const float* bi1, const float* bh1,
                            const float* bi2, const float* bh2, const float* bi3, const float* bh3,
                            float* __restrict__ bias) {
    int p = blockIdx.x * 256 + threadIdx.x;
    int q = p >> 5, g = (p >> 3) & 3, jj = p & 7;
    int j = q * 8 + jj;
    const float* a = (g == 0) ? bi0 : (g == 1) ? bi1 : (g == 2) ? bi2 : bi3;
    const float* b = (g == 0) ? bh0 : (g == 1) ? bh1 : (g == 2) ? bh2 : bh3;
    bias[p] = a[j] + b[j];
}

// ---------------- the whole LSTM in ONE persistent dispatch ----------------
// R16: spatial partition + halved sync population. R15's setprio was NULL
// (3095 ~= R13's 3072) -> xproj interference is CU resource contention, not
// issue arbitration; only placement fixes it. Grid = 256 = 1 block/CU:
// step blocks and xproj blocks own DISJOINT CUs (co-residency by capacity,
// scheduler-independent).
//   Blocks 0..127:   step path. WG owns 2 q-blocks (q0=2*(bid&63), q0+1),
//     bh = bid>>6. A-frags (h) SHARED across the two output tiles ->
//     h L3 traffic halves (8 MB/step), barrier arrivals halve (64/half,
//     8 groups x 8), per-wave MFMA doubles (32 in 4 indep chains).
//     VGPR ~300 (B 128 + A 64 + acc 64) -> __launch_bounds__(256,1).
//   Blocks 128..255: xproj path, 2 tiles/chunk each, dedicated CUs.
// Sync machinery = R13 (tree + merged-root poll, tid-0 only; chunk gates).
__global__ __launch_bounds__(256, 1) void k_mega(
    const float* __restrict__ x, const bf16_t* __restrict__ wxt,
    const float* __restrict__ bias, const bf16_t* __restrict__ whtf,
    bf16_t* __restrict__ xp, bf16_t* __restrict__ hbuf,
    float* __restrict__ out, uint32_t* __restrict__ bar)
{
    __shared__ float Pl[4][2][16][64];            // step: partials, 32 KB
    __shared__ __align__(16) bf16_t Hlds[2][256]; // step: h staging (per q-block)
    __shared__ __align__(16) bf16_t Al[8 * 64 * 8];  // xproj: A tile, 8 KB
    __shared__ __align__(16) bf16_t Bl[8 * 64 * 8];  // xproj: B tile, 8 KB
    const int tid  = threadIdx.x;

    if (blockIdx.x >= 128) {
        // ---------------- xproj producer path (dedicated CUs) ----------------
        const int xbid = blockIdx.x - 128;        // 0..127
        const int wv = tid >> 6;
        const int lane = tid & 63;
        const int mq = wv >> 1, nq = wv & 1;
        const int l15 = lane & 15, quad = lane >> 4;

        for (int sc = 0; sc < NCHUNK; ++sc) {
            // Slot reuse gate: chunk sc writes slot sc&1 (held chunk sc-2) —
            // wait until all 128 step WGs consumed it.
            if (sc >= 2) {
                if (tid == 0) {
                    while (__hip_atomic_load(&bar[CONS_IDX(sc - 2)], __ATOMIC_RELAXED,
                                             __HIP_MEMORY_SCOPE_AGENT) < 128u)
                        __builtin_amdgcn_s_sleep(2);
                }
                __syncthreads();
            }
            bf16_t* xps = xp + (size_t)(sc & 1) * XPSLOT_ELEMS;
            const int r_base = sc * (CHUNK * 64);

            for (int tt = 0; tt < 2; ++tt) {
                const int tile = xbid * 2 + tt;   // 0..255
                const int n0 = (tile & 31) * 128;
                const int rt = (tile >> 5) * 128;

                f32x4 acc[4][4] = {};
                for (int kk = 0; kk < I_DIM; kk += 32) {
                    __syncthreads();
                    #pragma unroll
                    for (int sidx = 0; sidx < 2; ++sidx) {
                        int s = tid + sidx * 256;
                        int mt = s >> 6, l = s & 63;
                        int m = l & 15, kb = (l >> 4) * 8;
                        int r = r_base + rt + mt * 16 + m;
                        int b = r & 63, si = r >> 6;
                        const float* gp = x + ((size_t)(b * S_DIM + si)) * I_DIM + kk + kb;
                        float4 v0 = *(const float4*)gp;
                        float4 v1 = *(const float4*)(gp + 4);
                        bf16x8 a;
                        a[0] = (bf16_t)v0.x; a[1] = (bf16_t)v0.y; a[2] = (bf16_t)v0.z; a[3] = (bf16_t)v0.w;
                        a[4] = (bf16_t)v1.x; a[5] = (bf16_t)v1.y; a[6] = (bf16_t)v1.z; a[7] = (bf16_t)v1.w;
                        *(bf16x8*)&Al[s * 8] = a;
                        bf16x8 bv = *(const bf16x8*)(wxt + (size_t)(n0 + mt * 16 + m) * I_DIM + kk + kb);
                        *(bf16x8*)&Bl[s * 8] = bv;
                    }
                    __syncthreads();
                    bf16x8 af[4], bfr[4];
                    #pragma unroll
                    for (int mt = 0; mt < 4; ++mt) af[mt]  = *(bf16x8*)&Al[((mq * 4 + mt) * 64 + lane) * 8];
                    #pragma unroll
                    for (int nt = 0; nt < 4; ++nt) bfr[nt] = *(bf16x8*)&Bl[((nq * 4 + nt) * 64 + lane) * 8];
                    #pragma unroll
                    for (int mt = 0; mt < 4; ++mt)
                        #pragma unroll
                        for (int nt = 0; nt < 4; ++nt)
                            acc[mt][nt] = __builtin_amdgcn_mfma_f32_16x16x32_bf16(af[mt], bfr[nt], acc[mt][nt], 0, 0, 0);
                }
                // Epilogue: agent-scope u16 stores (coherent for mid-dispatch read)
                #pragma unroll
                for (int nt = 0; nt < 4; ++nt) {
                    int colg = n0 + nq * 64 + nt * 16 + l15;
                    float bv = bias[colg];
                    #pragma unroll
                    for (int mt = 0; mt < 4; ++mt)
                        #pragma unroll
                        for (int r = 0; r < 4; ++r) {
                            int row = rt + mq * 64 + mt * 16 + quad * 4 + r;  // within chunk
                            bf16_t hb = (bf16_t)(acc[mt][nt][r] + bv);
                            __hip_atomic_store((uint16_t*)(xps + (size_t)row * G4 + colg),
                                               __builtin_bit_cast(unsigned short, hb),
                                               __ATOMIC_RELAXED, __HIP_MEMORY_SCOPE_AGENT);
                        }
                }
            }
            asm volatile("s_waitcnt vmcnt(0)" ::: "memory");  // all lanes drained
            __syncthreads();                                   // all waves drained
            if (tid == 0)
                __hip_atomic_fetch_add(&bar[XPD_IDX(sc)], 1u,
                                       __ATOMIC_RELAXED, __HIP_MEMORY_SCOPE_AGENT);
        }
        return;
    }

    // ---------------- step path (dedicated CUs, 2 q-blocks per WG) ----------
    const int w    = tid >> 6;                    // K-quarter index
    const int lane = tid & 63;
    const int bid  = blockIdx.x;
    const int qp   = bid & 63;                    // q-pair index
    const int q0   = qp * 2;
    const int bh   = bid >> 6;                    // batch half

    const int col  = lane & 31;
    const int ksel = lane >> 5;
    const int gt   = (lane >> 3) & 3;  // 0:i 1:f 2:g 3:o
    const int jj   = lane & 7;

    // Per-half barrier tree (monotonic u32, 64-spaced):
    //   group[bh][g]: bar[(bh*8+g)*64], g = qp&7, 8 arrivals/episode
    //   root[bh]:     bar[1024 + bh*64], 8 leader increments/episode
    uint32_t* grp  = bar + ((bh * 8 + (qp & 7)) << 6);
    uint32_t* root = bar + 1024 + (bh << 6);

    int rrow[4];
    #pragma unroll
    for (int e = 0; e < 4; ++e) rrow[e] = e + 8 * w + 4 * ksel;

    // Loop-invariant B fragments for BOTH q-blocks: loaded once, 512 steps.
    bf16x8 bfr0[16], bfr1[16];
    {
        const bf16_t* bb0 = whtf + ((size_t)q0 << 15) + (w << 13) + (lane << 3);
        const bf16_t* bb1 = whtf + ((size_t)(q0 + 1) << 15) + (w << 13) + (lane << 3);
        #pragma unroll
        for (int i = 0; i < 16; ++i) { bfr0[i] = *(const bf16x8*)(bb0 + i * 512);
                                       bfr1[i] = *(const bf16x8*)(bb1 + i * 512); }
    }

    // c-state in registers for the ENTIRE sequence (i-gate lanes only).
    float cst[2][4] = {};

    const int abase = (bh << 15) + (w << 13) + (lane << 3);  // h A-frag base (bf16 elems)

    for (int c = 0; c < NCHUNK; ++c) {
        // Wait for xp chunk c to be fully published (coarse, 1x per 16 steps).
        if (tid == 0) {
            while (__hip_atomic_load(&bar[XPD_IDX(c)], __ATOMIC_RELAXED,
                                     __HIP_MEMORY_SCOPE_AGENT) < 128u)
                __builtin_amdgcn_s_sleep(2);
        }
        __syncthreads();
        const uint16_t* xpc = (const uint16_t*)(xp + (size_t)(c & 1) * XPSLOT_ELEMS);

        for (int tl = 0; tl < CHUNK; ++tl) {
            const int t = c * CHUNK + tl;

            // h loads upfront — availability guaranteed by previous step's barrier.
            const uint64_t* hsrc = (const uint64_t*)(hbuf + ((t & 1) << 16) + abase);
            uint64_t hl0[16], hl1[16];
            #pragma unroll
            for (int i = 0; i < 16; ++i) {
                hl0[i] = __hip_atomic_load(hsrc + i * 128,     __ATOMIC_RELAXED, __HIP_MEMORY_SCOPE_AGENT);
                hl1[i] = __hip_atomic_load(hsrc + i * 128 + 1, __ATOMIC_RELAXED, __HIP_MEMORY_SCOPE_AGENT);
            }

            // xpr for both q-blocks: agent u16 loads (xp produced mid-dispatch).
            bf16_t xpr[2][4];
            #pragma unroll
            for (int qb = 0; qb < 2; ++qb)
                #pragma unroll
                for (int e = 0; e < 4; ++e) {
                    unsigned short v = __hip_atomic_load(
                        &xpc[(size_t)(tl * 64 + bh * 32 + rrow[e]) * G4 + (q0 + qb) * 32 + col],
                        __ATOMIC_RELAXED, __HIP_MEMORY_SCOPE_AGENT);
                    xpr[qb][e] = __builtin_bit_cast(bf16_t, v);
                }

            // 32 MFMA in 4 independent chains (2 per q-block), A shared.
            struct U2 { uint64_t a, b; };
            f32x16 a00 = {}, a01 = {}, a10 = {}, a11 = {};
            #pragma unroll
            for (int i = 0; i < 16; i += 2) {
                U2 t0{hl0[i],     hl1[i]};
                U2 t1{hl0[i + 1], hl1[i + 1]};
                bf16x8 A0 = __builtin_bit_cast(bf16x8, t0);
                bf16x8 A1 = __builtin_bit_cast(bf16x8, t1);
                a00 = __builtin_amdgcn_mfma_f32_32x32x16_bf16(A0, bfr0[i],     a00, 0, 0, 0);
                a10 = __builtin_amdgcn_mfma_f32_32x32x16_bf16(A0, bfr1[i],     a10, 0, 0, 0);
                a01 = __builtin_amdgcn_mfma_f32_32x32x16_bf16(A1, bfr0[i + 1], a01, 0, 0, 0);
                a11 = __builtin_amdgcn_mfma_f32_32x32x16_bf16(A1, bfr1[i + 1], a11, 0, 0, 0);
            }
            f32x16 acc_q0 = a00 + a01;
            f32x16 acc_q1 = a10 + a11;

            #pragma unroll
            for (int e = 0; e < 16; ++e) { Pl[w][0][e][lane] = acc_q0[e];
                                           Pl[w][1][e][lane] = acc_q1[e]; }
            __syncthreads();

            #pragma unroll
            for (int qb = 0; qb < 2; ++qb) {
                #pragma unroll
                for (int e = 0; e < 4; ++e) {
                    int eg = w * 4 + e;
                    float pre = Pl[0][qb][eg][lane] + Pl[1][qb][eg][lane]
                              + Pl[2][qb][eg][lane] + Pl[3][qb][eg][lane];
                    pre += (float)xpr[qb][e];
                    float a = (gt == 2) ? tanh_fast(pre) : sigm(pre);

                    float fv = __shfl_xor(a, 8, 64);
                    float gv = __shfl_xor(a, 16, 64);
                    float ov = __shfl_xor(a, 24, 64);
                    if (gt == 0) {
                        float cn = fv * cst[qb][e] + a * gv;
                        float hv = ov * tanh_fast(cn);
                        cst[qb][e] = cn;
                        Hlds[qb][rrow[e] * 8 + jj] = (bf16_t)hv;
                        if (t == S_DIM - 1) {
                            int rowg = bh * 32 + rrow[e];
                            int j = (q0 + qb) * 8 + jj;
                            out[rowg * H_DIM + j] = hv;            // h_T
                            out[65536 + rowg * H_DIM + j] = cn;    // c_T
                        }
                    }
                }
            }
            __syncthreads();   // Hlds complete; also fences Pl reuse next step

            // Publish both h slices (wave 0), drain, tree arrive + poll (lane 0).
            if (w == 0) {
                uint64_t v0 = *(const uint64_t*)&Hlds[0][lane * 4];
                uint64_t v1 = *(const uint64_t*)&Hlds[1][lane * 4];
                uint64_t* hb = (uint64_t*)hbuf + (((t + 1) & 1) << 14) + (bh << 13);
                __hip_atomic_store(hb + (q0 << 6) + lane,       v0, __ATOMIC_RELAXED, __HIP_MEMORY_SCOPE_AGENT);
                __hip_atomic_store(hb + ((q0 + 1) << 6) + lane, v1, __ATOMIC_RELAXED, __HIP_MEMORY_SCOPE_AGENT);
                if (t < S_DIM - 1) {
                    asm volatile("s_waitcnt vmcnt(0)" ::: "memory");  // h stores at L3
                    if (lane == 0) {
                        uint32_t old = __hip_atomic_fetch_add(grp, 1u,
                                                              __ATOMIC_RELAXED, __HIP_MEMORY_SCOPE_AGENT);
                        if ((old & 7u) == 7u)                        // 8 arrivals -> leader
                            __hip_atomic_fetch_add(root, 1u,
                                                   __ATOMIC_RELAXED, __HIP_MEMORY_SCOPE_AGENT);
                        uint32_t target = (uint32_t)(8 * (t + 1));
                        while (__hip_atomic_load(root, __ATOMIC_RELAXED,
                                                 __HIP_MEMORY_SCOPE_AGENT) < target) {}
                    }
                }
            }
            if (t < S_DIM - 1) __syncthreads();   // release all waves
        }

        // Chunk consumed: xproj may overwrite this xp slot (for chunk c+2).
        if (tid == 0)
            __hip_atomic_fetch_add(&bar[CONS_IDX(c)], 1u,
                                   __ATOMIC_RELAXED, __HIP_MEMORY_SCOPE_AGENT);
    }
}

extern "C" void kernel_launch(void* const* d_in, const int* in_sizes, int n_in,
                              void* d_out, int out_size, void* d_ws, size_t ws_size,
                              hipStream_t stream) {
    const float* x   = (const float*)d_in[0];
    const float* wii = (const float*)d_in[1];
    const float* bii = (const float*)d_in[2];
    const float* whi = (const float*)d_in[3];
    const float* bhi = (const float*)d_in[4];
    const float* wif = (const float*)d_in[5];
    const float* bif = (const float*)d_in[6];
    const float* whf = (const float*)d_in[7];
    const float* bhf = (const float*)d_in[8];
    const float* wig = (const float*)d_in[9];
    const float* big = (const float*)d_in[10];
    const float* whg = (const float*)d_in[11];
    const float* bhg = (const float*)d_in[12];
    const float* wio = (const float*)d_in[13];
    const float* bio = (const float*)d_in[14];
    const float* who = (const float*)d_in[15];
    const float* bho = (const float*)d_in[16];

    char* ws = (char*)d_ws;
    bf16_t*   wxt  = (bf16_t*)(ws + O_WXT);
    bf16_t*   whtf = (bf16_t*)(ws + O_WHTF);
    float*    bias = (float*)(ws + O_BIAS);
    bf16_t*   hbuf = (bf16_t*)(ws + O_HBUF);
    uint32_t* bar  = (uint32_t*)(ws + O_BAR);
    bf16_t*   xp   = (bf16_t*)(ws + O_XP);

    hipMemsetAsync(hbuf, 0, 256 * 1024, stream);   // both h slots = 0 (h0)
    hipMemsetAsync(bar,  0, 32 * 1024, stream);    // all counters (reset each replay)

    k_pack_wx<<<8192, 256, 0, stream>>>(wii, wif, wig, wio, wxt);
    k_pack_whf<<<16384, 256, 0, stream>>>(whi, whf, whg, who, whtf);
    k_pack_bias<<<16, 256, 0, stream>>>(bii, bhi, bif, bhf, big, bhg, bio, bho, bias);

    float* out = (float*)d_out;
    void* args[] = { (void*)&x, (void*)&wxt, (void*)&bias, (void*)&whtf,
                     (void*)&xp, (void*)&hbuf, (void*)&out, (void*)&bar };
    hipError_t err = hipLaunchCooperativeKernel((const void*)k_mega, dim3(256), dim3(256),
                                                args, 0, stream);
    if (err != hipSuccess) {
        // Plain-launch fallback: grid 256 = 1 block/CU on a 256-CU chip, so
        // all blocks are co-resident regardless of dispatch order.
        k_mega<<<256, 256, 0, stream>>>(x, wxt, bias, whtf, xp, hbuf, out, bar);
    }
}

// Round 11
// 3556.644 us; speedup vs baseline: 1.0644x; 1.0644x over previous
//
#include <hip/hip_runtime.h>
#include <hip/hip_bf16.h>
#include <stdint.h>

typedef __bf16 bf16_t;
typedef bf16_t bf16x8 __attribute__((ext_vector_type(8)));
typedef float  f32x4  __attribute__((ext_vector_type(4)));
typedef float  f32x16 __attribute__((ext_vector_type(16)));

#define I_DIM 512
#define H_DIM 1024
#define B_DIM 64
#define S_DIM 512
#define G4    4096   // 4*H
#define CHUNK 16     // steps per xp ring slot
#define NCHUNK (S_DIM / CHUNK)
#define XPSLOT_ELEMS ((size_t)CHUNK * 64 * G4)   // 1024*4096 bf16 = 8 MB

// ---------------- workspace layout (bytes) — total ~34 MB ----------------
#define O_WXT   0x0000000ULL  // [4096][512]  bf16 = 4 MB   (packed WxT, row-major)
#define O_WHTF  0x0400000ULL  // [128][64][64][8] bf16 = 8 MB (Wh in MFMA B-frag order)
#define O_BIAS  0x0C00000ULL  // [4096] f32 = 16 KB
#define O_HBUF  0x0D00000ULL  // 2 slots * 128 KB (h in A-frag order) = 256 KB
#define O_BAR   0x0D40000ULL  // 32 KB counters: tree barrier + xp_done[] + consumed[]
#define O_XP    0x1200000ULL  // 2 slots * [1024][4096] bf16 = 16 MB

// bar[] u32 indices (64-spaced to avoid false sharing)
#define XPD_IDX(c)  (2048 + (c) * 64)   // xp chunk c published (256 arrivals)
#define CONS_IDX(c) (4096 + (c) * 64)   // xp chunk c consumed  (256 arrivals)

__device__ __forceinline__ float sigm(float x)      { return 1.f / (1.f + __expf(-x)); }
__device__ __forceinline__ float tanh_fast(float x) { return 1.f - 2.f / (__expf(2.f * x) + 1.f); }

// Packed gate-column permutation: packed col p = q*32 + g*8 + jj  <->  hidden j = q*8+jj, gate g (0:i 1:f 2:g 3:o)

__global__ void k_pack_wx(const float* __restrict__ w0, const float* __restrict__ w1,
                          const float* __restrict__ w2, const float* __restrict__ w3,
                          bf16_t* __restrict__ wxt) {
    int tid = blockIdx.x * 256 + threadIdx.x;
    int k = tid >> 12;
    int p = tid & 4095;
    int q = p >> 5, g = (p >> 3) & 3, jj = p & 7;
    int j = q * 8 + jj;
    const float* src = (g == 0) ? w0 : (g == 1) ? w1 : (g == 2) ? w2 : w3;
    wxt[(size_t)p * I_DIM + k] = (bf16_t)src[k * H_DIM + j];
}

// Wh -> global MFMA B-fragment order: whtf[q][ks][lane][8]
//   element = WhT[p = q*32 + (lane&31)][k = ks*16 + (lane>>5)*8 + e]
__global__ void k_pack_whf(const float* __restrict__ w0, const float* __restrict__ w1,
                           const float* __restrict__ w2, const float* __restrict__ w3,
                           bf16_t* __restrict__ whtf) {
    int idx = blockIdx.x * 256 + threadIdx.x;     // 0..4194303
    int e    = idx & 7;
    int lane = (idx >> 3) & 63;
    int ks   = (idx >> 9) & 63;
    int q    = idx >> 15;                          // 0..127
    int k = ks * 16 + (lane >> 5) * 8 + e;
    int c = lane & 31;
    int g = c >> 3, jj = c & 7;
    int j = q * 8 + jj;
    const float* src = (g == 0) ? w0 : (g == 1) ? w1 : (g == 2) ? w2 : w3;
    whtf[idx] = (bf16_t)src[k * H_DIM + j];
}

__global__ void k_pack_bias(const float* bi0, const float* bh0, const float* bi1, const float* bh1,
                            const float* bi2, const float* bh2, const float* bi3, const float* bh3,
                            float* __restrict__ bias) {
    int p = blockIdx.x * 256 + threadIdx.x;
    int q = p >> 5, g = (p >> 3) & 3, jj = p & 7;
    int j = q * 8 + jj;
    const float* a = (g == 0) ? bi0 : (g == 1) ? bi1 : (g == 2) ? bi2 : bi3;
    const float* b = (g == 0) ? bh0 : (g == 1) ? bh1 : (g == 2) ? bh2 : bh3;
    bias[p] = a[j] + b[j];
}

// ---------------- the whole LSTM in ONE persistent dispatch ----------------
// R17 = R15 (best family: mega 3072-3095) + xpr prefetch-through-barrier.
// R16 post-mortem: widening to 2 q-blocks/WG spilled (VGPR_Count 164 vs
// ~210 live) -> weights re-streamed per step; regression. Twice-falsified.
// Ledger: step 6.0us = exec ~1.8 + tree ~2.3 + skew/interference ~1.9.
// This round's single refinement (ordering-only, no new sync semantics):
// xpr is chunk-static and barrier-independent, but R13/R15 issued it AFTER
// the 32 h loads -> it queued behind them on the post-release critical
// path. Prefetch step t+1's xpr BEFORE arriving at step t's barrier (in
// flight through the wait); post-release path = h loads -> MFMA -> epilogue
// only. tl=0's xpr prefetched right after the chunk gate. No cross-chunk
// prefetch (next chunk's xp unpublished). Everything else = R15.
__global__ __launch_bounds__(256, 2) void k_mega(
    const float* __restrict__ x, const bf16_t* __restrict__ wxt,
    const float* __restrict__ bias, const bf16_t* __restrict__ whtf,
    bf16_t* __restrict__ xp, bf16_t* __restrict__ hbuf,
    float* __restrict__ out, uint32_t* __restrict__ bar)
{
    __shared__ float Pl[4][16][64];               // step: partials, 16 KB
    __shared__ __align__(16) bf16_t Hlds[256];    // step: h staging
    __shared__ __align__(16) bf16_t Al[8 * 64 * 8];  // xproj: A tile, 8 KB
    __shared__ __align__(16) bf16_t Bl[8 * 64 * 8];  // xproj: B tile, 8 KB
    const int tid  = threadIdx.x;

    if (blockIdx.x >= 256) {
        // ---------------- xproj producer path ----------------
        const int xbid = blockIdx.x - 256;        // 0..255
        const int n0 = (xbid & 31) * 128;         // col tile
        const int rt = (xbid >> 5) * 128;         // row tile within chunk (0..896)
        const int wv = tid >> 6;
        const int lane = tid & 63;
        const int mq = wv >> 1, nq = wv & 1;
        const int l15 = lane & 15, quad = lane >> 4;

        for (int sc = 0; sc < NCHUNK; ++sc) {
            // Slot reuse gate: chunk sc writes slot sc&1, previously holding
            // chunk sc-2 — wait until all 256 step WGs consumed it.
            if (sc >= 2) {
                if (tid == 0) {
                    while (__hip_atomic_load(&bar[CONS_IDX(sc - 2)], __ATOMIC_RELAXED,
                                             __HIP_MEMORY_SCOPE_AGENT) < 256u)
                        __builtin_amdgcn_s_sleep(2);
                }
                __syncthreads();
            }
            bf16_t* xps = xp + (size_t)(sc & 1) * XPSLOT_ELEMS;
            const int r_base = sc * (CHUNK * 64);

            f32x4 acc[4][4] = {};
            for (int kk = 0; kk < I_DIM; kk += 32) {
                __syncthreads();
                #pragma unroll
                for (int sidx = 0; sidx < 2; ++sidx) {
                    int s = tid + sidx * 256;
                    int mt = s >> 6, l = s & 63;
                    int m = l & 15, kb = (l >> 4) * 8;
                    int r = r_base + rt + mt * 16 + m;
                    int b = r & 63, si = r >> 6;
                    const float* gp = x + ((size_t)(b * S_DIM + si)) * I_DIM + kk + kb;
                    float4 v0 = *(const float4*)gp;
                    float4 v1 = *(const float4*)(gp + 4);
                    bf16x8 a;
                    a[0] = (bf16_t)v0.x; a[1] = (bf16_t)v0.y; a[2] = (bf16_t)v0.z; a[3] = (bf16_t)v0.w;
                    a[4] = (bf16_t)v1.x; a[5] = (bf16_t)v1.y; a[6] = (bf16_t)v1.z; a[7] = (bf16_t)v1.w;
                    *(bf16x8*)&Al[s * 8] = a;
                    bf16x8 bv = *(const bf16x8*)(wxt + (size_t)(n0 + mt * 16 + m) * I_DIM + kk + kb);
                    *(bf16x8*)&Bl[s * 8] = bv;
                }
                __syncthreads();
                bf16x8 af[4], bfr[4];
                #pragma unroll
                for (int mt = 0; mt < 4; ++mt) af[mt]  = *(bf16x8*)&Al[((mq * 4 + mt) * 64 + lane) * 8];
                #pragma unroll
                for (int nt = 0; nt < 4; ++nt) bfr[nt] = *(bf16x8*)&Bl[((nq * 4 + nt) * 64 + lane) * 8];
                #pragma unroll
                for (int mt = 0; mt < 4; ++mt)
                    #pragma unroll
                    for (int nt = 0; nt < 4; ++nt)
                        acc[mt][nt] = __builtin_amdgcn_mfma_f32_16x16x32_bf16(af[mt], bfr[nt], acc[mt][nt], 0, 0, 0);
            }
            // Epilogue: agent-scope u16 stores (coherent for mid-dispatch read)
            #pragma unroll
            for (int nt = 0; nt < 4; ++nt) {
                int colg = n0 + nq * 64 + nt * 16 + l15;
                float bv = bias[colg];
                #pragma unroll
                for (int mt = 0; mt < 4; ++mt)
                    #pragma unroll
                    for (int r = 0; r < 4; ++r) {
                        int row = rt + mq * 64 + mt * 16 + quad * 4 + r;  // within chunk
                        bf16_t hb = (bf16_t)(acc[mt][nt][r] + bv);
                        __hip_atomic_store((uint16_t*)(xps + (size_t)row * G4 + colg),
                                           __builtin_bit_cast(unsigned short, hb),
                                           __ATOMIC_RELAXED, __HIP_MEMORY_SCOPE_AGENT);
                    }
            }
            asm volatile("s_waitcnt vmcnt(0)" ::: "memory");  // all lanes drained
            __syncthreads();                                   // all waves drained
            if (tid == 0)
                __hip_atomic_fetch_add(&bar[XPD_IDX(sc)], 1u,
                                       __ATOMIC_RELAXED, __HIP_MEMORY_SCOPE_AGENT);
        }
        return;
    }

    // ---------------- step path ----------------
    const int w    = tid >> 6;                    // K-quarter index
    const int lane = tid & 63;
    const int bid  = blockIdx.x;
    const int q    = bid & 127;                   // packed col-block (32 cols)
    const int bh   = bid >> 7;                    // batch half

    const int col  = lane & 31;
    const int ksel = lane >> 5;
    const int gt   = (lane >> 3) & 3;  // 0:i 1:f 2:g 3:o
    const int jj   = lane & 7;

    // Per-half barrier tree (monotonic u32, 64-spaced):
    //   group[bh][g]: bar[(bh*8+g)*64], g = q&7, 16 arrivals/episode
    //   root[bh]:     bar[1024 + bh*64], 8 leader increments/episode
    // Pollers wait root >= 8*(t+1)  (epoch tier merged into root).
    uint32_t* grp  = bar + ((bh * 8 + (q & 7)) << 6);
    uint32_t* root = bar + 1024 + (bh << 6);

    int rrow[4];
    #pragma unroll
    for (int e = 0; e < 4; ++e) rrow[e] = e + 8 * w + 4 * ksel;

    // Loop-invariant B fragments: loaded ONCE for all 512 steps.
    const bf16_t* bb = whtf + ((size_t)q << 15) + (w << 13) + (lane << 3);
    bf16x8 bfr[16];
    #pragma unroll
    for (int i = 0; i < 16; ++i) bfr[i] = *(const bf16x8*)(bb + i * 512);

    // c-state in registers for the ENTIRE sequence (i-gate lanes only).
    float cst[4] = {0.f, 0.f, 0.f, 0.f};

    const int abase = (bh << 15) + (w << 13) + (lane << 3);  // h A-frag base (bf16 elements)

    for (int c = 0; c < NCHUNK; ++c) {
        // Wait for xp chunk c to be fully published (coarse, 1x per 16 steps).
        if (tid == 0) {
            while (__hip_atomic_load(&bar[XPD_IDX(c)], __ATOMIC_RELAXED,
                                     __HIP_MEMORY_SCOPE_AGENT) < 256u)
                __builtin_amdgcn_s_sleep(2);
        }
        __syncthreads();
        const uint16_t* xpc = (const uint16_t*)(xp + (size_t)(c & 1) * XPSLOT_ELEMS);

        // Prefetch xpr for tl=0 (barrier-independent, chunk-published).
        bf16_t xprN[4];
        #pragma unroll
        for (int e = 0; e < 4; ++e) {
            unsigned short v = __hip_atomic_load(
                &xpc[(size_t)(0 * 64 + bh * 32 + rrow[e]) * G4 + q * 32 + col],
                __ATOMIC_RELAXED, __HIP_MEMORY_SCOPE_AGENT);
            xprN[e] = __builtin_bit_cast(bf16_t, v);
        }

        for (int tl = 0; tl < CHUNK; ++tl) {
            const int t = c * CHUNK + tl;

            // Current step's xpr = last iteration's prefetch.
            bf16_t xpr[4];
            #pragma unroll
            for (int e = 0; e < 4; ++e) xpr[e] = xprN[e];

            // h loads upfront — availability guaranteed by previous step's
            // barrier. These are the ONLY loads on the post-release path.
            const uint64_t* hsrc = (const uint64_t*)(hbuf + ((t & 1) << 16) + abase);
            uint64_t hl0[16], hl1[16];
            #pragma unroll
            for (int i = 0; i < 16; ++i) {
                hl0[i] = __hip_atomic_load(hsrc + i * 128,     __ATOMIC_RELAXED, __HIP_MEMORY_SCOPE_AGENT);
                hl1[i] = __hip_atomic_load(hsrc + i * 128 + 1, __ATOMIC_RELAXED, __HIP_MEMORY_SCOPE_AGENT);
            }

            struct U2 { uint64_t a, b; };
            f32x16 acc0 = {}, acc1 = {}, acc2 = {}, acc3 = {};
            #pragma unroll
            for (int i = 0; i < 16; i += 4) {
                U2 t0{hl0[i + 0], hl1[i + 0]};
                U2 t1{hl0[i + 1], hl1[i + 1]};
                U2 t2{hl0[i + 2], hl1[i + 2]};
                U2 t3{hl0[i + 3], hl1[i + 3]};
                acc0 = __builtin_amdgcn_mfma_f32_32x32x16_bf16(__builtin_bit_cast(bf16x8, t0), bfr[i + 0], acc0, 0, 0, 0);
                acc1 = __builtin_amdgcn_mfma_f32_32x32x16_bf16(__builtin_bit_cast(bf16x8, t1), bfr[i + 1], acc1, 0, 0, 0);
                acc2 = __builtin_amdgcn_mfma_f32_32x32x16_bf16(__builtin_bit_cast(bf16x8, t2), bfr[i + 2], acc2, 0, 0, 0);
                acc3 = __builtin_amdgcn_mfma_f32_32x32x16_bf16(__builtin_bit_cast(bf16x8, t3), bfr[i + 3], acc3, 0, 0, 0);
            }
            f32x16 accs = acc0 + acc1 + acc2 + acc3;

            #pragma unroll
            for (int e = 0; e < 16; ++e) Pl[w][e][lane] = accs[e];
            __syncthreads();

            #pragma unroll
            for (int e = 0; e < 4; ++e) {
                int eg = w * 4 + e;
                float pre = Pl[0][eg][lane] + Pl[1][eg][lane] + Pl[2][eg][lane] + Pl[3][eg][lane];
                pre += (float)xpr[e];
                float a = (gt == 2) ? tanh_fast(pre) : sigm(pre);

                float fv = __shfl_xor(a, 8, 64);
                float gv = __shfl_xor(a, 16, 64);
                float ov = __shfl_xor(a, 24, 64);
                if (gt == 0) {
                    float cn = fv * cst[e] + a * gv;
                    float hv = ov * tanh_fast(cn);
                    cst[e] = cn;
                    Hlds[rrow[e] * 8 + jj] = (bf16_t)hv;
                    if (t == S_DIM - 1) {
                        int rowg = bh * 32 + rrow[e];
                        int j = q * 8 + jj;
                        out[rowg * H_DIM + j] = hv;            // h_T
                        out[65536 + rowg * H_DIM + j] = cn;    // c_T
                    }
                }
            }

            // Prefetch NEXT step's xpr before the barrier — flies through
            // the wait. (Within-chunk only; next chunk's xp unpublished.)
            if (tl < CHUNK - 1) {
                #pragma unroll
                for (int e = 0; e < 4; ++e) {
                    unsigned short v = __hip_atomic_load(
                        &xpc[(size_t)((tl + 1) * 64 + bh * 32 + rrow[e]) * G4 + q * 32 + col],
                        __ATOMIC_RELAXED, __HIP_MEMORY_SCOPE_AGENT);
                    xprN[e] = __builtin_bit_cast(bf16_t, v);
                }
            }

            __syncthreads();   // Hlds complete; also fences Pl reuse next step

            // Publish h slice (wave 0), drain, tree arrive + poll (lane 0).
            if (w == 0) {
                uint64_t v = *(const uint64_t*)&Hlds[lane * 4];
                uint64_t* hdst = (uint64_t*)hbuf + (((t + 1) & 1) << 14)
                               + (bh << 13) + (q << 6) + lane;
                __hip_atomic_store(hdst, v, __ATOMIC_RELAXED, __HIP_MEMORY_SCOPE_AGENT);
                if (t < S_DIM - 1) {
                    asm volatile("s_waitcnt vmcnt(0)" ::: "memory");  // h store at L3
                    if (lane == 0) {
                        uint32_t old = __hip_atomic_fetch_add(grp, 1u,
                                                              __ATOMIC_RELAXED, __HIP_MEMORY_SCOPE_AGENT);
                        if ((old & 15u) == 15u)                      // 16 arrivals -> leader
                            __hip_atomic_fetch_add(root, 1u,
                                                   __ATOMIC_RELAXED, __HIP_MEMORY_SCOPE_AGENT);
                        uint32_t target = (uint32_t)(8 * (t + 1));
                        while (__hip_atomic_load(root, __ATOMIC_RELAXED,
                                                 __HIP_MEMORY_SCOPE_AGENT) < target) {}
                    }
                }
            }
            if (t < S_DIM - 1) __syncthreads();   // release all waves
        }

        // Chunk consumed: xproj may overwrite this xp slot (for chunk c+2).
        if (tid == 0)
            __hip_atomic_fetch_add(&bar[CONS_IDX(c)], 1u,
                                   __ATOMIC_RELAXED, __HIP_MEMORY_SCOPE_AGENT);
    }
}

extern "C" void kernel_launch(void* const* d_in, const int* in_sizes, int n_in,
                              void* d_out, int out_size, void* d_ws, size_t ws_size,
                              hipStream_t stream) {
    const float* x   = (const float*)d_in[0];
    const float* wii = (const float*)d_in[1];
    const float* bii = (const float*)d_in[2];
    const float* whi = (const float*)d_in[3];
    const float* bhi = (const float*)d_in[4];
    const float* wif = (const float*)d_in[5];
    const float* bif = (const float*)d_in[6];
    const float* whf = (const float*)d_in[7];
    const float* bhf = (const float*)d_in[8];
    const float* wig = (const float*)d_in[9];
    const float* big = (const float*)d_in[10];
    const float* whg = (const float*)d_in[11];
    const float* bhg = (const float*)d_in[12];
    const float* wio = (const float*)d_in[13];
    const float* bio = (const float*)d_in[14];
    const float* who = (const float*)d_in[15];
    const float* bho = (const float*)d_in[16];

    char* ws = (char*)d_ws;
    bf16_t*   wxt  = (bf16_t*)(ws + O_WXT);
    bf16_t*   whtf = (bf16_t*)(ws + O_WHTF);
    float*    bias = (float*)(ws + O_BIAS);
    bf16_t*   hbuf = (bf16_t*)(ws + O_HBUF);
    uint32_t* bar  = (uint32_t*)(ws + O_BAR);
    bf16_t*   xp   = (bf16_t*)(ws + O_XP);

    hipMemsetAsync(hbuf, 0, 256 * 1024, stream);   // both h slots = 0 (h0)
    hipMemsetAsync(bar,  0, 32 * 1024, stream);    // all counters (reset each replay)

    k_pack_wx<<<8192, 256, 0, stream>>>(wii, wif, wig, wio, wxt);
    k_pack_whf<<<16384, 256, 0, stream>>>(whi, whf, whg, who, whtf);
    k_pack_bias<<<16, 256, 0, stream>>>(bii, bhi, bif, bhf, big, bhg, bio, bho, bias);

    float* out = (float*)d_out;
    void* args[] = { (void*)&x, (void*)&wxt, (void*)&bias, (void*)&whtf,
                     (void*)&xp, (void*)&hbuf, (void*)&out, (void*)&bar };
    hipError_t err = hipLaunchCooperativeKernel((const void*)k_mega, dim3(512), dim3(256),
                                                args, 0, stream);
    if (err != hipSuccess) {
        // Plain-launch fallback: capacity (2 blocks/CU x 256 CU) == grid, so
        // all 512 blocks are co-resident regardless of dispatch order.
        k_mega<<<512, 256, 0, stream>>>(x, wxt, bias, whtf, xp, hbuf, out, bar);
    }
}